// Round 8
// baseline (1404.734 us; speedup 1.0000x reference)
//
#include <hip/hip_runtime.h>
#include <cstdint>
#include <cstddef>

#define NNODES 131072
#define NEDGES 1048576
#define NPROB  64

typedef _Float16 half8 __attribute__((ext_vector_type(8)));
typedef _Float16 half4v __attribute__((ext_vector_type(4)));
typedef _Float16 half2v __attribute__((ext_vector_type(2)));
typedef float float4v __attribute__((ext_vector_type(4)));

__device__ __forceinline__ float fsigm(float x) {
    return __builtin_amdgcn_rcpf(1.0f + __expf(-x));
}
__device__ __forceinline__ float ftanh(float x) {
    return 1.0f - 2.0f * __builtin_amdgcn_rcpf(__expf(2.0f * x) + 1.0f);
}

__device__ __forceinline__ void async16(void* lds, const void* g) {
    __builtin_amdgcn_global_load_lds(
        (const __attribute__((address_space(1))) uint32_t*)g,
        (__attribute__((address_space(3))) uint32_t*)lds, 16, 0, 0);
}

// ---------------- weight prep (batched) ----------------
// two 128x128 transposes -> contiguous dst
__global__ __launch_bounds__(256) void tr_cvt2(const float* __restrict__ s0,
    const float* __restrict__ s1, _Float16* __restrict__ dst)
{
    int i = blockIdx.x * 256 + threadIdx.x;     // 32768
    int half = i >> 14, r = i & 16383;
    int m = r >> 7, k = r & 127;
    const float* s = half ? s1 : s0;
    dst[i] = (_Float16)s[(size_t)k * 128 + m];
}

// dst[m*K + k] = src[k*sstride + m]
__global__ __launch_bounds__(256) void tr_cvt(const float* __restrict__ src,
    _Float16* __restrict__ dst, int K, int M, int sstride)
{
    int i = blockIdx.x * 256 + threadIdx.x;
    if (i < M * K) {
        int m = i / K, k = i % K;
        dst[i] = (_Float16)src[(size_t)k * sstride + m];
    }
}

__global__ __launch_bounds__(256) void cvt16_2(const float* __restrict__ a,
    const float* __restrict__ b, _Float16* __restrict__ d)
{
    int i = blockIdx.x * 256 + threadIdx.x;     // 98304
    d[i] = (_Float16)((i < 49152) ? a[i] : b[i - 49152]);
}

// all four Wc[g][j] = sum_k Wih[g][k] * W[j][k]  -> contiguous [4][384][128] fp16
__global__ __launch_bounds__(256) void combine_gru4(const float* __restrict__ W1ih,
    const float* __restrict__ W1, const float* __restrict__ W2ih,
    const float* __restrict__ W2, _Float16* __restrict__ outw)
{
    int i = blockIdx.x * 256 + threadIdx.x;     // 196608
    int set = i / 49152, r = i - set * 49152;
    int g = r >> 7, j = r & 127;
    const float* Wih = (set < 2) ? W1ih : W2ih;
    const float* W = (set == 0) ? W1 : (set == 1) ? W1 + 16384
                   : (set == 2) ? W2 : W2 + 16384;
    const float* a = Wih + (size_t)g * 128;
    const float* b = W + (size_t)j * 128;
    float s = 0.0f;
#pragma unroll 8
    for (int k = 0; k < 128; ++k) s = fmaf(a[k], b[k], s);
    outw[i] = (_Float16)s;
}

// At[m][j] = sum_k Wg2[j][k] * Wl[k][m]   -> fp16 [256][128]
__global__ __launch_bounds__(256) void combine_headA(const float* __restrict__ Wg2,
    const float* __restrict__ Wl, _Float16* __restrict__ At)
{
    int i = blockIdx.x * 256 + threadIdx.x;   // 32768
    int m = i >> 7, j = i & 127;
    float s = 0.0f;
#pragma unroll 8
    for (int k = 0; k < 128; ++k)
        s = fmaf(Wg2[(size_t)j * 128 + k], Wl[(size_t)k * 256 + m], s);
    At[i] = (_Float16)s;
}

// Bf[t][m] = sum_k Wg2[t][k] * Wl[128+k][m]   -> fp32 [128][256]
__global__ __launch_bounds__(256) void combine_headB(const float* __restrict__ Wg2,
    const float* __restrict__ Wl, float* __restrict__ Bf)
{
    int i = blockIdx.x * 256 + threadIdx.x;   // 32768
    int t = i >> 8, m = i & 255;
    float s = 0.0f;
#pragma unroll 8
    for (int k = 0; k < 128; ++k)
        s = fmaf(Wg2[(size_t)t * 128 + k], Wl[(size_t)(128 + k) * 256 + m], s);
    Bf[i] = s;
}

// cvec[m] = bl[m] + sum_k bg2[k]*(Wl[k][m] + Wl[128+k][m])
__global__ __launch_bounds__(256) void combine_c(const float* __restrict__ bg2,
    const float* __restrict__ Wl, const float* __restrict__ bl, float* __restrict__ cvec)
{
    int m = threadIdx.x;
    float s = bl[m];
#pragma unroll 8
    for (int k = 0; k < 128; ++k)
        s = fmaf(bg2[k], Wl[(size_t)k * 256 + m] + Wl[(size_t)(128 + k) * 256 + m], s);
    cvec[m] = s;
}

// ---------------- CSR build: histogram -> scan -> fill ----------------
__global__ __launch_bounds__(256) void deg_hist(const int* __restrict__ dst,
                                                int* __restrict__ deg)
{
    int e = blockIdx.x * 256 + threadIdx.x;
    atomicAdd(&deg[dst[e]], 1);
}

__global__ __launch_bounds__(256) void scan1(const int* __restrict__ deg,
    int* __restrict__ offs, int* __restrict__ bsum)
{
    __shared__ int s[256];
    int b = blockIdx.x, tid = threadIdx.x;
    int4 v = ((const int4*)deg)[b * 256 + tid];
    int t0 = v.x, t1 = t0 + v.y, t2 = t1 + v.z, t3 = t2 + v.w;
    s[tid] = t3;
    __syncthreads();
    for (int off = 1; off < 256; off <<= 1) {
        int x = (tid >= off) ? s[tid - off] : 0;
        __syncthreads();
        if (tid >= off) s[tid] += x;
        __syncthreads();
    }
    int excl = tid ? s[tid - 1] : 0;
    int4 o; o.x = excl; o.y = excl + t0; o.z = excl + t1; o.w = excl + t2;
    ((int4*)offs)[b * 256 + tid] = o;
    if (tid == 255) bsum[b] = s[255];
}

__global__ __launch_bounds__(128) void scan2(int* __restrict__ bsum)
{
    __shared__ int s[128];
    int tid = threadIdx.x;
    s[tid] = bsum[tid];
    __syncthreads();
    for (int off = 1; off < 128; off <<= 1) {
        int x = (tid >= off) ? s[tid - off] : 0;
        __syncthreads();
        if (tid >= off) s[tid] += x;
        __syncthreads();
    }
    bsum[tid] = tid ? s[tid - 1] : 0;
}

__global__ __launch_bounds__(256) void scan3(int* __restrict__ offs,
    const int* __restrict__ bsum, int* __restrict__ pos)
{
    int i = blockIdx.x * 256 + threadIdx.x;
    int v = offs[i] + bsum[i >> 10];
    offs[i] = v;
    pos[i] = v;
    if (i == 0) offs[NNODES] = NEDGES;
}

__global__ __launch_bounds__(256) void csr_fill(const int* __restrict__ src,
    const int* __restrict__ dst, const float* __restrict__ ew,
    int* __restrict__ pos, int2* __restrict__ csr)
{
    int e = blockIdx.x * 256 + threadIdx.x;
    int slot = atomicAdd(&pos[dst[e]], 1);
    unsigned long long pk = (unsigned long long)(unsigned)src[e]
                          | ((unsigned long long)__float_as_uint(ew[e]) << 32);
    __builtin_nontemporal_store(pk, (unsigned long long*)csr + slot);
}

// ---------------- emb1: x = relu(G @ W1 + b1) -> fp16 ----------------
__global__ __launch_bounds__(256) void emb1_kernel(const float* __restrict__ G,
    const float* __restrict__ W1, const float* __restrict__ b1, _Float16* __restrict__ Y)
{
    int idx = blockIdx.x * 256 + threadIdx.x;
    int n = idx >> 7, c = idx & 127;
    const float* g = G + (size_t)n * 8;
    float y = b1[c];
#pragma unroll
    for (int k = 0; k < 8; ++k) y = fmaf(g[k], W1[k * 128 + c], y);
    Y[(size_t)n * 128 + c] = (_Float16)fmaxf(y, 0.0f);
}

// ---------------- MFMA GEMM: out = act(X @ WtT + bias [+gproj]) -------------
// FINAL: instead of storing a [N][128] result, dot rows with wl3 -> outf[n].
template<int K, int MCH, bool INF16, bool RELU, bool SEGADD, bool FINAL>
__global__ __launch_bounds__(256, 2) void gemm_mfma(
    const void* __restrict__ Xin, int xstride,
    const _Float16* __restrict__ Wt,
    const float* __restrict__ bias,
    _Float16* __restrict__ out1, int ostride,
    const float* __restrict__ gproj, const int* __restrict__ seg,
    const float* __restrict__ wl3, const float* __restrict__ bl3p,
    float* __restrict__ outf)
{
    constexpr int ROWB = 2 * K;
    constexpr int SPR  = K / 8;
    __shared__ __align__(16) char Xs[128 * ROWB];
    __shared__ __align__(16) char Ws[128 * ROWB];
    const int tid = threadIdx.x, wid = tid >> 6, l = tid & 63;
    const int lr = l & 15, lk = l >> 4;
    const int wrow = wid * 32;

    for (int mc = 0; mc < MCH; ++mc) {
        __syncthreads();
        {
            const _Float16* wsrc = Wt + (size_t)mc * 128 * K;
            for (int s0 = wid * 64; s0 < 128 * SPR; s0 += 256) {
                int s = s0 + l;
                int row = s / SPR, sub = s % SPR;
                int ksub = sub ^ (row & 7);
                async16(Ws + s0 * 16, (const char*)(wsrc + (size_t)row * K) + ksub * 16);
            }
        }
        asm volatile("s_waitcnt vmcnt(0)" ::: "memory");
        __syncthreads();

        half8 bfr[32];
        if constexpr (K == 128) {
#pragma unroll
            for (int ct = 0; ct < 8; ++ct)
#pragma unroll
                for (int ks = 0; ks < 4; ++ks) {
                    int row = ct * 16 + lr;
                    bfr[ct * 4 + ks] = *(const half8*)(Ws + row * ROWB +
                        ((ks * 64 + lk * 16) ^ ((row & 7) << 4)));
                }
        }

        for (int t = blockIdx.x; t < NNODES / 128; t += gridDim.x) {
            const int nbase = t * 128;
            __syncthreads();
            if constexpr (INF16) {
                const _Float16* xsrc = (const _Float16*)Xin;
                for (int s0 = wid * 64; s0 < 128 * SPR; s0 += 256) {
                    int s = s0 + l;
                    int row = s / SPR, sub = s % SPR;
                    int ksub = sub ^ (row & 7);
                    async16(Xs + s0 * 16,
                            (const char*)(xsrc + (size_t)(nbase + row) * xstride) + ksub * 16);
                }
                asm volatile("s_waitcnt vmcnt(0)" ::: "memory");
            } else {
                const float* xsrc = (const float*)Xin;
                for (int s = tid; s < 128 * SPR; s += 256) {
                    int row = s / SPR, sub = s % SPR;
                    int ksub = sub ^ (row & 7);
                    const float* p = xsrc + (size_t)(nbase + row) * xstride + ksub * 8;
                    float4 u = ((const float4*)p)[0];
                    float4 v = ((const float4*)p)[1];
                    half8 hv;
                    hv[0] = (_Float16)u.x; hv[1] = (_Float16)u.y;
                    hv[2] = (_Float16)u.z; hv[3] = (_Float16)u.w;
                    hv[4] = (_Float16)v.x; hv[5] = (_Float16)v.y;
                    hv[6] = (_Float16)v.z; hv[7] = (_Float16)v.w;
                    *(half8*)(Xs + s * 16) = hv;
                }
            }
            __syncthreads();

            float4v acc[2][8];
#pragma unroll
            for (int i = 0; i < 2; ++i)
#pragma unroll
                for (int j = 0; j < 8; ++j)
#pragma unroll
                    for (int q = 0; q < 4; ++q) acc[i][j][q] = 0.0f;

            if constexpr (K == 128) {
#pragma unroll
                for (int rt = 0; rt < 2; ++rt) {
                    half8 a[4];
                    int row = wrow + rt * 16 + lr;
#pragma unroll
                    for (int ks = 0; ks < 4; ++ks)
                        a[ks] = *(const half8*)(Xs + row * ROWB +
                            ((ks * 64 + lk * 16) ^ ((row & 7) << 4)));
#pragma unroll
                    for (int ct = 0; ct < 8; ++ct)
#pragma unroll
                        for (int ks = 0; ks < 4; ++ks)
                            acc[rt][ct] = __builtin_amdgcn_mfma_f32_16x16x32_f16(
                                a[ks], bfr[ct * 4 + ks], acc[rt][ct], 0, 0, 0);
                }
            } else {   // K == 256
#pragma unroll
                for (int kc = 0; kc < 2; ++kc) {
#pragma unroll
                    for (int ct = 0; ct < 8; ++ct)
#pragma unroll
                        for (int ks = 0; ks < 4; ++ks) {
                            int row = ct * 16 + lr;
                            bfr[ct * 4 + ks] = *(const half8*)(Ws + row * ROWB +
                                (((kc * 4 + ks) * 64 + lk * 16) ^ ((row & 7) << 4)));
                        }
#pragma unroll
                    for (int rt = 0; rt < 2; ++rt) {
                        half8 a[4];
                        int row = wrow + rt * 16 + lr;
#pragma unroll
                        for (int ks = 0; ks < 4; ++ks)
                            a[ks] = *(const half8*)(Xs + row * ROWB +
                                (((kc * 4 + ks) * 64 + lk * 16) ^ ((row & 7) << 4)));
#pragma unroll
                        for (int ct = 0; ct < 8; ++ct)
#pragma unroll
                            for (int ks = 0; ks < 4; ++ks)
                                acc[rt][ct] = __builtin_amdgcn_mfma_f32_16x16x32_f16(
                                    a[ks], bfr[ct * 4 + ks], acc[rt][ct], 0, 0, 0);
                    }
                }
            }

            if constexpr (FINAL) {
                const float bl3v = bl3p[0];
                float part[2][4];
#pragma unroll
                for (int rt = 0; rt < 2; ++rt)
#pragma unroll
                    for (int j = 0; j < 4; ++j) part[rt][j] = 0.0f;
#pragma unroll
                for (int rt = 0; rt < 2; ++rt)
#pragma unroll
                for (int ct = 0; ct < 8; ++ct) {
                    const int col = ct * 16 + lr;
                    const float wv = wl3[col];
                    const float bv = bias[col];
#pragma unroll
                    for (int j = 0; j < 4; ++j) {
                        float v = fmaxf(acc[rt][ct][j] + bv, 0.0f);
                        part[rt][j] = fmaf(v, wv, part[rt][j]);
                    }
                }
#pragma unroll
                for (int rt = 0; rt < 2; ++rt)
#pragma unroll
                for (int j = 0; j < 4; ++j) {
                    float s = part[rt][j];
                    s += __shfl_xor(s, 1);
                    s += __shfl_xor(s, 2);
                    s += __shfl_xor(s, 4);
                    s += __shfl_xor(s, 8);
                    if (lr == 0)
                        outf[nbase + wrow + rt * 16 + lk * 4 + j] = s + bl3v;
                }
            } else {
#pragma unroll
                for (int rt = 0; rt < 2; ++rt)
#pragma unroll
                for (int ct = 0; ct < 8; ++ct) {
                    const int col = ct * 16 + lr;
                    float bv = 0.0f;
                    if (bias) bv = bias[mc * 128 + col];
#pragma unroll
                    for (int j = 0; j < 4; ++j) {
                        const int n = nbase + wrow + rt * 16 + lk * 4 + j;
                        float v = acc[rt][ct][j] + bv;
                        if constexpr (SEGADD)
                            v += gproj[(size_t)seg[n] * 256 + mc * 128 + col];
                        if constexpr (RELU) v = fmaxf(v, 0.0f);
                        out1[(size_t)n * ostride + mc * 128 + col] = (_Float16)v;
                    }
                }
            }
        }
    }
}

// ---------------- fused gather + GRU: hout = GRUCell(gather(hin)@Wc, hin@Whh) ----
// hin read-only (gather + tile + h_old); hout written. Ping-pong across iterations.
__global__ __launch_bounds__(512, 2) void gru_fused(
    const _Float16* __restrict__ hin,   // [N][128]
    _Float16* __restrict__ hout,        // [N][128]
    const int2* __restrict__ csr, const int* __restrict__ offs,
    const _Float16* __restrict__ Wc,    // combined Wih*W^T fp16 [384][128]
    const _Float16* __restrict__ Whh,   // [384][128] fp16
    const float* __restrict__ bih, const float* __restrict__ bhh,
    int relu_out)
{
    __shared__ __align__(16) char As[128 * 256];
    __shared__ __align__(16) char Hs[128 * 256];
    __shared__ __align__(16) char Wb[2][128 * 256];
    const int tid = threadIdx.x, wid = tid >> 6, l = tid & 63;
    const int lr = l & 15, lk = l >> 4;
    const int wr = wid >> 1, wc = wid & 1;
    const int nbase = blockIdx.x * 128;

    auto stageT = [&](char* dst, const _Float16* src) {
        for (int s0 = wid * 64; s0 < 2048; s0 += 512) {
            int s = s0 + l;
            int row = s >> 4, sub = s & 15;
            int ksub = sub ^ (row & 7);
            async16(dst + s0 * 16, (const char*)(src + (size_t)row * 128) + ksub * 16);
        }
    };

    // fire-and-forget staging (completes under the vmcnt(0) below)
    stageT(Hs, hin + (size_t)nbase * 128);
    stageT(Wb[0], Wc);

    // gather this wave's 16 rows into As (swizzled), 2 nodes interleaved, 4-deep
    {
        const int cb = l * 4;            // lane's byte offset within a row (2 cols)
        for (int rr = wid * 16; rr < wid * 16 + 16; rr += 2) {
            const int n0 = nbase + rr, n1 = n0 + 1;
            int i0 = offs[n0], E0 = offs[n0 + 1];
            int i1 = E0, E1 = offs[n1 + 1];
            float a00 = 0.f, a01 = 0.f, a10 = 0.f, a11 = 0.f;
            while (i0 < E0 || i1 < E1) {
                int c0 = E0 - i0; c0 = c0 > 4 ? 4 : c0;
                int c1 = E1 - i1; c1 = c1 > 4 ? 4 : c1;
                int2 e0[4], e1[4];
#pragma unroll
                for (int k = 0; k < 4; ++k) {
                    if (k < c0) e0[k] = csr[i0 + k];
                    if (k < c1) e1[k] = csr[i1 + k];
                }
                half2v v0[4], v1[4];
#pragma unroll
                for (int k = 0; k < 4; ++k) {
                    if (k < c0) v0[k] = *(const half2v*)(hin + (size_t)e0[k].x * 128 + l * 2);
                    if (k < c1) v1[k] = *(const half2v*)(hin + (size_t)e1[k].x * 128 + l * 2);
                }
#pragma unroll
                for (int k = 0; k < 4; ++k) {
                    if (k < c0) {
                        float w = __int_as_float(e0[k].y);
                        a00 = fmaf((float)v0[k][0], w, a00);
                        a01 = fmaf((float)v0[k][1], w, a01);
                    }
                    if (k < c1) {
                        float w = __int_as_float(e1[k].y);
                        a10 = fmaf((float)v1[k][0], w, a10);
                        a11 = fmaf((float)v1[k][1], w, a11);
                    }
                }
                i0 += c0; i1 += c1;
            }
            half2v o0; o0[0] = (_Float16)a00; o0[1] = (_Float16)a01;
            half2v o1; o1[0] = (_Float16)a10; o1[1] = (_Float16)a11;
            *(half2v*)(As + rr * 256 + (((cb >> 4) ^ (rr & 7)) << 4) + (cb & 15)) = o0;
            *(half2v*)(As + (rr + 1) * 256 + (((cb >> 4) ^ ((rr + 1) & 7)) << 4) + (cb & 15)) = o1;
        }
    }

    float4v accA[2][4], accB[2][4], rg[2][4], zg[2][4];
    half8 aAg[2][4], aH[2][4];

#pragma unroll
    for (int c = 0; c < 6; ++c) {
        asm volatile("s_waitcnt vmcnt(0)" ::: "memory");
        __syncthreads();
        if (c < 5) {
            const int nc = c + 1;
            const _Float16* wsrc = ((nc & 1) ? Whh : Wc) + (size_t)(nc >> 1) * 16384;
            stageT(Wb[nc & 1], wsrc);
        }
        if (c == 0) {
#pragma unroll
            for (int rt = 0; rt < 2; ++rt) {
                const int row = wr * 32 + rt * 16 + lr;
#pragma unroll
                for (int ks = 0; ks < 4; ++ks) {
                    const int off = row * 256 + ((ks * 64 + lk * 16) ^ ((row & 7) << 4));
                    aAg[rt][ks] = *(const half8*)(As + off);
                    aH[rt][ks]  = *(const half8*)(Hs + off);
                }
            }
        }

        auto& af  = (c & 1) ? aH : aAg;
        auto& acc = (c & 1) ? accB : accA;
#pragma unroll
        for (int rt = 0; rt < 2; ++rt)
#pragma unroll
            for (int ct = 0; ct < 4; ++ct)
#pragma unroll
                for (int q = 0; q < 4; ++q) acc[rt][ct][q] = 0.0f;

        const char* wb = Wb[c & 1];
#pragma unroll
        for (int ct = 0; ct < 4; ++ct) {
            const int rowb = wc * 64 + ct * 16 + lr;
#pragma unroll
            for (int ks = 0; ks < 4; ++ks) {
                half8 b = *(const half8*)(wb + rowb * 256 +
                    ((ks * 64 + lk * 16) ^ ((rowb & 7) << 4)));
                acc[0][ct] = __builtin_amdgcn_mfma_f32_16x16x32_f16(af[0][ks], b, acc[0][ct], 0, 0, 0);
                acc[1][ct] = __builtin_amdgcn_mfma_f32_16x16x32_f16(af[1][ks], b, acc[1][ct], 0, 0, 0);
            }
        }

        if (c == 1) {
#pragma unroll
            for (int rt = 0; rt < 2; ++rt)
#pragma unroll
            for (int ct = 0; ct < 4; ++ct) {
                const int col = wc * 64 + ct * 16 + lr;
                const float bb = bih[col] + bhh[col];
#pragma unroll
                for (int j = 0; j < 4; ++j)
                    rg[rt][ct][j] = fsigm(accA[rt][ct][j] + accB[rt][ct][j] + bb);
            }
        } else if (c == 3) {
#pragma unroll
            for (int rt = 0; rt < 2; ++rt)
#pragma unroll
            for (int ct = 0; ct < 4; ++ct) {
                const int col = wc * 64 + ct * 16 + lr;
                const float bb = bih[128 + col] + bhh[128 + col];
#pragma unroll
                for (int j = 0; j < 4; ++j)
                    zg[rt][ct][j] = fsigm(accA[rt][ct][j] + accB[rt][ct][j] + bb);
            }
        } else if (c == 5) {
#pragma unroll
            for (int rt = 0; rt < 2; ++rt)
#pragma unroll
            for (int ct = 0; ct < 4; ++ct) {
                const int col = wc * 64 + ct * 16 + lr;
                const float bi = bih[256 + col], bh = bhh[256 + col];
                const int c2 = col * 2;
#pragma unroll
                for (int j = 0; j < 4; ++j) {
                    const int row = wr * 32 + rt * 16 + lk * 4 + j;
                    const int n = nbase + row;
                    float nv = ftanh(accA[rt][ct][j] + bi +
                                     rg[rt][ct][j] * (accB[rt][ct][j] + bh));
                    float hold = (float)*(const _Float16*)(Hs + row * 256 +
                        (((c2 >> 4) ^ (row & 7)) << 4) + (c2 & 15));
                    float z = zg[rt][ct][j];
                    float hn = (1.0f - z) * nv + z * hold;
                    if (relu_out) hn = fmaxf(hn, 0.0f);
                    hout[(size_t)n * 128 + col] = (_Float16)hn;
                }
            }
        }
    }
}

// ---------------- segment sums (seg sorted) ----------------
__global__ __launch_bounds__(256) void seg_sum(const _Float16* __restrict__ x,
    const int* __restrict__ seg, float* __restrict__ sums, float* __restrict__ counts)
{
    int cg = threadIdx.x & 31, rs = threadIdx.x >> 5;
    int r0 = blockIdx.x * 256 + rs * 32;
    float a0 = 0, a1 = 0, a2 = 0, a3 = 0, cnt = 0;
    int cur = seg[r0];
    for (int i = 0; i < 32; ++i) {
        int n = r0 + i;
        int p = seg[n];
        if (p != cur) {
            atomicAdd(&sums[(size_t)cur * 128 + cg * 4 + 0], a0);
            atomicAdd(&sums[(size_t)cur * 128 + cg * 4 + 1], a1);
            atomicAdd(&sums[(size_t)cur * 128 + cg * 4 + 2], a2);
            atomicAdd(&sums[(size_t)cur * 128 + cg * 4 + 3], a3);
            if (cg == 0) atomicAdd(&counts[cur], cnt);
            a0 = a1 = a2 = a3 = 0; cnt = 0; cur = p;
        }
        half4v v = *(const half4v*)(x + (size_t)n * 128 + cg * 4);
        a0 += (float)v[0]; a1 += (float)v[1]; a2 += (float)v[2]; a3 += (float)v[3];
        cnt += 1.0f;
    }
    atomicAdd(&sums[(size_t)cur * 128 + cg * 4 + 0], a0);
    atomicAdd(&sums[(size_t)cur * 128 + cg * 4 + 1], a1);
    atomicAdd(&sums[(size_t)cur * 128 + cg * 4 + 2], a2);
    atomicAdd(&sums[(size_t)cur * 128 + cg * 4 + 3], a3);
    if (cg == 0) atomicAdd(&counts[cur], cnt);
}

// ---------------- gproj2[p][m] = cvec[m] + sum_t ymean[t]*Bf[t][m] ----------------
__global__ __launch_bounds__(256) void gproj2_kernel(const float* __restrict__ sums,
    const float* __restrict__ counts, const float* __restrict__ Bf,
    const float* __restrict__ cvec, float* __restrict__ gproj2)
{
    __shared__ float gm[128];
    int p = blockIdx.x, m = threadIdx.x;
    if (m < 128) gm[m] = sums[(size_t)p * 128 + m] / fmaxf(counts[p], 1.0f);
    __syncthreads();
    float acc = cvec[m];
#pragma unroll 8
    for (int k = 0; k < 128; ++k)
        acc = fmaf(gm[k], Bf[(size_t)k * 256 + m], acc);
    gproj2[(size_t)p * 256 + m] = acc;
}

extern "C" void kernel_launch(void* const* d_in, const int* in_sizes, int n_in,
                              void* d_out, int out_size, void* d_ws, size_t ws_size,
                              hipStream_t stream)
{
    (void)in_sizes; (void)n_in; (void)out_size; (void)ws_size;

    const float* G     = (const float*)d_in[0];
    const int*   ei    = (const int*)d_in[1];
    const float* ew    = (const float*)d_in[2];
    const int*   seg   = (const int*)d_in[4];
    const float* Wemb1 = (const float*)d_in[5];  const float* bemb1 = (const float*)d_in[6];
    const float* Wemb2 = (const float*)d_in[7];  const float* bemb2 = (const float*)d_in[8];
    const float* c1W   = (const float*)d_in[9];
    const float* c1Wih = (const float*)d_in[10]; const float* c1Whh = (const float*)d_in[11];
    const float* c1bih = (const float*)d_in[12]; const float* c1bhh = (const float*)d_in[13];
    const float* c2W   = (const float*)d_in[14];
    const float* c2Wih = (const float*)d_in[15]; const float* c2Whh = (const float*)d_in[16];
    const float* c2bih = (const float*)d_in[17]; const float* c2bhh = (const float*)d_in[18];
    const float* Wg1   = (const float*)d_in[19]; const float* bg1   = (const float*)d_in[20];
    const float* Wg2   = (const float*)d_in[21]; const float* bg2   = (const float*)d_in[22];
    const float* Wl    = (const float*)d_in[23]; const float* bl    = (const float*)d_in[24];
    const float* Wl2   = (const float*)d_in[25]; const float* bl2   = (const float*)d_in[26];
    const float* Wl3   = (const float*)d_in[27]; const float* bl3   = (const float*)d_in[28];

    const int* srcp = ei;
    const int* dstp = ei + NEDGES;

    char* ws = (char*)d_ws;
    const size_t NBH = (size_t)NNODES * 128 * 2;   // 32MB
    const size_t U1B = (size_t)NNODES * 256 * 2;   // 64MB

    _Float16* hA   = (_Float16*)ws;                 // h ping
    _Float16* hB   = (_Float16*)(ws + NBH);         // y
    _Float16* u1   = (_Float16*)(ws + 2 * NBH);     // [N][256]
    _Float16* hC   = (_Float16*)(ws + 2 * NBH + U1B); // h pong
    char*     aux  = ws + 3 * NBH + U1B;
    float* sums    = (float*)aux;                    // 32KB
    float* counts  = (float*)(aux + 32768);          // 1KB
    float* gproj2  = (float*)(aux + 33792);          // 64KB
    int*   deg     = (int*)(aux + 33792 + 65536);
    int*   offs    = deg + NNODES;
    int*   pos     = offs + NNODES + 64;
    int2*  csr     = (int2*)(pos + NNODES);
    char*  wtb     = (char*)csr + (size_t)NEDGES * 8;

    _Float16* wt_emb2 = (_Float16*)wtb;                    // [128][128]
    _Float16* wt_g1   = wt_emb2 + 16384;                   // [128][128] (contig w/ emb2)
    _Float16* wt_l2   = wt_g1 + 16384;                     // [128][256]
    _Float16* wt_hh1  = wt_l2 + 32768;                     // [384][128]
    _Float16* wt_hh2  = wt_hh1 + 49152;                    // (contig w/ hh1)
    _Float16* wc0     = wt_hh2 + 49152;                    // [4][384][128] contiguous
    _Float16* At      = wc0 + 4 * 49152;                   // [256][128]
    float*    Bf      = (float*)(At + 32768);              // [128][256] fp32
    float*    cvec    = Bf + 32768;                        // [256]

    // ---- weight prep (batched) ----
    tr_cvt2<<<128, 256, 0, stream>>>(Wemb2, Wg1, wt_emb2);
    tr_cvt<<<128, 256, 0, stream>>>(Wl2, wt_l2, 256, 128, 128);
    cvt16_2<<<384, 256, 0, stream>>>(c1Whh, c2Whh, wt_hh1);
    combine_gru4<<<768, 256, 0, stream>>>(c1Wih, c1W, c2Wih, c2W, wc0);
    combine_headA<<<128, 256, 0, stream>>>(Wg2, Wl, At);
    combine_headB<<<128, 256, 0, stream>>>(Wg2, Wl, Bf);
    combine_c<<<1, 256, 0, stream>>>(bg2, Wl, bl, cvec);

    // ---- CSR build ----
    hipMemsetAsync(deg, 0, NNODES * 4, stream);
    deg_hist<<<NEDGES / 256, 256, 0, stream>>>(dstp, deg);
    scan1<<<128, 256, 0, stream>>>(deg, offs, pos);
    scan2<<<1, 128, 0, stream>>>(pos);
    scan3<<<NNODES / 256, 256, 0, stream>>>(offs, pos, deg);
    csr_fill<<<NEDGES / 256, 256, 0, stream>>>(srcp, dstp, ew, deg, csr);

    // ---- embeddings ----
    emb1_kernel<<<NNODES * 128 / 256, 256, 0, stream>>>(G, Wemb1, bemb1, hB);
    gemm_mfma<128, 1, true, true, false, false><<<512, 256, 0, stream>>>(
        hB, 128, wt_emb2, bemb2, hA, 128, nullptr, nullptr, nullptr, nullptr, nullptr);

    // ---- 2 GatedGraphConv layers x 2 GRU iterations (gather fused, h ping-pong) --
    const _Float16* wcs[2][2] = { { wc0, wc0 + 49152 }, { wc0 + 2 * 49152, wc0 + 3 * 49152 } };
    const _Float16* whh[2] = { wt_hh1, wt_hh2 };
    const float* bihs[2] = { c1bih, c2bih };
    const float* bhhs[2] = { c1bhh, c2bhh };
    _Float16* hcur = hA;
    _Float16* halt = hC;
    for (int cv = 0; cv < 2; ++cv) {
        for (int lyr = 0; lyr < 2; ++lyr) {
            gru_fused<<<NNODES / 128, 512, 0, stream>>>(
                hcur, halt, csr, offs, wcs[cv][lyr], whh[cv],
                bihs[cv], bhhs[cv], (lyr == 1) ? 1 : 0);
            _Float16* tmp = hcur; hcur = halt; halt = tmp;
        }
    }
    // 4 iterations -> result back in hA (hcur == hA)

    // ---- head: y = relu(x@Wg1+bg1); Wg2 folded into At/Bf/cvec ----
    gemm_mfma<128, 1, true, true, false, false><<<512, 256, 0, stream>>>(
        hcur, 128, wt_g1, bg1, hB, 128, nullptr, nullptr, nullptr, nullptr, nullptr);

    hipMemsetAsync(sums, 0, 33792, stream);
    seg_sum<<<NNODES / 256, 256, 0, stream>>>(hB, seg, sums, counts);
    gproj2_kernel<<<NPROB, 256, 0, stream>>>(sums, counts, Bf, cvec, gproj2);

    // ---- u1 = relu(y @ At^T + gproj2[seg]) [N,256] ----
    gemm_mfma<128, 2, true, true, true, false><<<512, 256, 0, stream>>>(
        hB, 128, At, nullptr, u1, 256, gproj2, seg, nullptr, nullptr, nullptr);
    // ---- out[n] = relu(u1@Wl2+bl2) . Wl3 + bl3  (final dot fused) ----
    gemm_mfma<256, 1, true, true, false, true><<<256, 256, 0, stream>>>(
        u1, 256, wt_l2, bl2, nullptr, 0, nullptr, nullptr, Wl3, bl3, (float*)d_out);
}

// Round 9
// 934.889 us; speedup vs baseline: 1.5026x; 1.5026x over previous
//
#include <hip/hip_runtime.h>
#include <cstdint>
#include <cstddef>

#define NNODES 131072
#define NEDGES 1048576
#define NPROB  64

typedef _Float16 half8 __attribute__((ext_vector_type(8)));
typedef _Float16 half4v __attribute__((ext_vector_type(4)));
typedef _Float16 half2v __attribute__((ext_vector_type(2)));
typedef float float4v __attribute__((ext_vector_type(4)));

__device__ __forceinline__ float fsigm(float x) {
    return __builtin_amdgcn_rcpf(1.0f + __expf(-x));
}
__device__ __forceinline__ float ftanh(float x) {
    return 1.0f - 2.0f * __builtin_amdgcn_rcpf(__expf(2.0f * x) + 1.0f);
}

__device__ __forceinline__ void async16(void* lds, const void* g) {
    __builtin_amdgcn_global_load_lds(
        (const __attribute__((address_space(1))) uint32_t*)g,
        (__attribute__((address_space(3))) uint32_t*)lds, 16, 0, 0);
}

// ---------------- weight prep (batched) ----------------
// two 128x128 transposes -> contiguous dst
__global__ __launch_bounds__(256) void tr_cvt2(const float* __restrict__ s0,
    const float* __restrict__ s1, _Float16* __restrict__ dst)
{
    int i = blockIdx.x * 256 + threadIdx.x;     // 32768
    int half = i >> 14, r = i & 16383;
    int m = r >> 7, k = r & 127;
    const float* s = half ? s1 : s0;
    dst[i] = (_Float16)s[(size_t)k * 128 + m];
}

// dst[m*K + k] = src[k*sstride + m]
__global__ __launch_bounds__(256) void tr_cvt(const float* __restrict__ src,
    _Float16* __restrict__ dst, int K, int M, int sstride)
{
    int i = blockIdx.x * 256 + threadIdx.x;
    if (i < M * K) {
        int m = i / K, k = i % K;
        dst[i] = (_Float16)src[(size_t)k * sstride + m];
    }
}

__global__ __launch_bounds__(256) void cvt16_2(const float* __restrict__ a,
    const float* __restrict__ b, _Float16* __restrict__ d)
{
    int i = blockIdx.x * 256 + threadIdx.x;     // 98304
    d[i] = (_Float16)((i < 49152) ? a[i] : b[i - 49152]);
}

// all four Wc[g][j] = sum_k Wih[g][k] * W[j][k]  -> contiguous [4][384][128] fp16
__global__ __launch_bounds__(256) void combine_gru4(const float* __restrict__ W1ih,
    const float* __restrict__ W1, const float* __restrict__ W2ih,
    const float* __restrict__ W2, _Float16* __restrict__ outw)
{
    int i = blockIdx.x * 256 + threadIdx.x;     // 196608
    int set = i / 49152, r = i - set * 49152;
    int g = r >> 7, j = r & 127;
    const float* Wih = (set < 2) ? W1ih : W2ih;
    const float* W = (set == 0) ? W1 : (set == 1) ? W1 + 16384
                   : (set == 2) ? W2 : W2 + 16384;
    const float* a = Wih + (size_t)g * 128;
    const float* b = W + (size_t)j * 128;
    float s = 0.0f;
#pragma unroll 8
    for (int k = 0; k < 128; ++k) s = fmaf(a[k], b[k], s);
    outw[i] = (_Float16)s;
}

// At[m][j] = sum_k Wg2[j][k] * Wl[k][m]   -> fp16 [256][128]
__global__ __launch_bounds__(256) void combine_headA(const float* __restrict__ Wg2,
    const float* __restrict__ Wl, _Float16* __restrict__ At)
{
    int i = blockIdx.x * 256 + threadIdx.x;   // 32768
    int m = i >> 7, j = i & 127;
    float s = 0.0f;
#pragma unroll 8
    for (int k = 0; k < 128; ++k)
        s = fmaf(Wg2[(size_t)j * 128 + k], Wl[(size_t)k * 256 + m], s);
    At[i] = (_Float16)s;
}

// Bf[t][m] = sum_k Wg2[t][k] * Wl[128+k][m]   -> fp32 [128][256]
__global__ __launch_bounds__(256) void combine_headB(const float* __restrict__ Wg2,
    const float* __restrict__ Wl, float* __restrict__ Bf)
{
    int i = blockIdx.x * 256 + threadIdx.x;   // 32768
    int t = i >> 8, m = i & 255;
    float s = 0.0f;
#pragma unroll 8
    for (int k = 0; k < 128; ++k)
        s = fmaf(Wg2[(size_t)t * 128 + k], Wl[(size_t)(128 + k) * 256 + m], s);
    Bf[i] = s;
}

// cvec[m] = bl[m] + sum_k bg2[k]*(Wl[k][m] + Wl[128+k][m])
__global__ __launch_bounds__(256) void combine_c(const float* __restrict__ bg2,
    const float* __restrict__ Wl, const float* __restrict__ bl, float* __restrict__ cvec)
{
    int m = threadIdx.x;
    float s = bl[m];
#pragma unroll 8
    for (int k = 0; k < 128; ++k)
        s = fmaf(bg2[k], Wl[(size_t)k * 256 + m] + Wl[(size_t)(128 + k) * 256 + m], s);
    cvec[m] = s;
}

// ---------------- CSR build: histogram -> scan -> fill ----------------
__global__ __launch_bounds__(256) void deg_hist(const int* __restrict__ dst,
                                                int* __restrict__ deg)
{
    int e = blockIdx.x * 256 + threadIdx.x;
    atomicAdd(&deg[dst[e]], 1);
}

__global__ __launch_bounds__(256) void scan1(const int* __restrict__ deg,
    int* __restrict__ offs, int* __restrict__ bsum)
{
    __shared__ int s[256];
    int b = blockIdx.x, tid = threadIdx.x;
    int4 v = ((const int4*)deg)[b * 256 + tid];
    int t0 = v.x, t1 = t0 + v.y, t2 = t1 + v.z, t3 = t2 + v.w;
    s[tid] = t3;
    __syncthreads();
    for (int off = 1; off < 256; off <<= 1) {
        int x = (tid >= off) ? s[tid - off] : 0;
        __syncthreads();
        if (tid >= off) s[tid] += x;
        __syncthreads();
    }
    int excl = tid ? s[tid - 1] : 0;
    int4 o; o.x = excl; o.y = excl + t0; o.z = excl + t1; o.w = excl + t2;
    ((int4*)offs)[b * 256 + tid] = o;
    if (tid == 255) bsum[b] = s[255];
}

__global__ __launch_bounds__(128) void scan2(int* __restrict__ bsum)
{
    __shared__ int s[128];
    int tid = threadIdx.x;
    s[tid] = bsum[tid];
    __syncthreads();
    for (int off = 1; off < 128; off <<= 1) {
        int x = (tid >= off) ? s[tid - off] : 0;
        __syncthreads();
        if (tid >= off) s[tid] += x;
        __syncthreads();
    }
    bsum[tid] = tid ? s[tid - 1] : 0;
}

__global__ __launch_bounds__(256) void scan3(int* __restrict__ offs,
    const int* __restrict__ bsum, int* __restrict__ pos)
{
    int i = blockIdx.x * 256 + threadIdx.x;
    int v = offs[i] + bsum[i >> 10];
    offs[i] = v;
    pos[i] = v;
    if (i == 0) offs[NNODES] = NEDGES;
}

__global__ __launch_bounds__(256) void csr_fill(const int* __restrict__ src,
    const int* __restrict__ dst, const float* __restrict__ ew,
    int* __restrict__ pos, int2* __restrict__ csr)
{
    int e = blockIdx.x * 256 + threadIdx.x;
    int slot = atomicAdd(&pos[dst[e]], 1);
    unsigned long long pk = (unsigned long long)(unsigned)src[e]
                          | ((unsigned long long)__float_as_uint(ew[e]) << 32);
    __builtin_nontemporal_store(pk, (unsigned long long*)csr + slot);
}

// ---------------- gather aggregate (4-deep ILP): agg[n] = sum ew_e * h[src_e] ----
__global__ __launch_bounds__(256) void gather_agg(const _Float16* __restrict__ t,
    const int2* __restrict__ csr, const int* __restrict__ offs,
    _Float16* __restrict__ agg)
{
    int node = blockIdx.x * 4 + (threadIdx.x >> 6);
    int lane = threadIdx.x & 63;
    int i = offs[node], end = offs[node + 1];
    float a0 = 0.0f, a1 = 0.0f;
    for (; i + 4 <= end; i += 4) {
        int2 e0 = csr[i], e1 = csr[i + 1], e2 = csr[i + 2], e3 = csr[i + 3];
        half2v v0 = *(const half2v*)(t + (size_t)e0.x * 128 + lane * 2);
        half2v v1 = *(const half2v*)(t + (size_t)e1.x * 128 + lane * 2);
        half2v v2 = *(const half2v*)(t + (size_t)e2.x * 128 + lane * 2);
        half2v v3 = *(const half2v*)(t + (size_t)e3.x * 128 + lane * 2);
        float w0 = __int_as_float(e0.y), w1 = __int_as_float(e1.y);
        float w2 = __int_as_float(e2.y), w3 = __int_as_float(e3.y);
        a0 = fmaf((float)v0[0], w0, a0); a1 = fmaf((float)v0[1], w0, a1);
        a0 = fmaf((float)v1[0], w1, a0); a1 = fmaf((float)v1[1], w1, a1);
        a0 = fmaf((float)v2[0], w2, a0); a1 = fmaf((float)v2[1], w2, a1);
        a0 = fmaf((float)v3[0], w3, a0); a1 = fmaf((float)v3[1], w3, a1);
    }
    for (; i < end; ++i) {
        int2 e = csr[i];
        float w = __int_as_float(e.y);
        half2v v = *(const half2v*)(t + (size_t)e.x * 128 + lane * 2);
        a0 = fmaf((float)v[0], w, a0);
        a1 = fmaf((float)v[1], w, a1);
    }
    half2v o; o[0] = (_Float16)a0; o[1] = (_Float16)a1;
    *(half2v*)(agg + (size_t)node * 128 + lane * 2) = o;
}

// ---------------- emb1: x = relu(G @ W1 + b1) -> fp16 ----------------
__global__ __launch_bounds__(256) void emb1_kernel(const float* __restrict__ G,
    const float* __restrict__ W1, const float* __restrict__ b1, _Float16* __restrict__ Y)
{
    int idx = blockIdx.x * 256 + threadIdx.x;
    int n = idx >> 7, c = idx & 127;
    const float* g = G + (size_t)n * 8;
    float y = b1[c];
#pragma unroll
    for (int k = 0; k < 8; ++k) y = fmaf(g[k], W1[k * 128 + c], y);
    Y[(size_t)n * 128 + c] = (_Float16)fmaxf(y, 0.0f);
}

// ---------------- MFMA GEMM: out = act(X @ WtT + bias [+gproj]) -------------
// FINAL: instead of storing a [N][128] result, dot rows with wl3 -> outf[n].
template<int K, int MCH, bool INF16, bool RELU, bool SEGADD, bool FINAL>
__global__ __launch_bounds__(256, 2) void gemm_mfma(
    const void* __restrict__ Xin, int xstride,
    const _Float16* __restrict__ Wt,
    const float* __restrict__ bias,
    _Float16* __restrict__ out1, int ostride,
    const float* __restrict__ gproj, const int* __restrict__ seg,
    const float* __restrict__ wl3, const float* __restrict__ bl3p,
    float* __restrict__ outf)
{
    constexpr int ROWB = 2 * K;
    constexpr int SPR  = K / 8;
    __shared__ __align__(16) char Xs[128 * ROWB];
    __shared__ __align__(16) char Ws[128 * ROWB];
    const int tid = threadIdx.x, wid = tid >> 6, l = tid & 63;
    const int lr = l & 15, lk = l >> 4;
    const int wrow = wid * 32;

    for (int mc = 0; mc < MCH; ++mc) {
        __syncthreads();
        {
            const _Float16* wsrc = Wt + (size_t)mc * 128 * K;
            for (int s0 = wid * 64; s0 < 128 * SPR; s0 += 256) {
                int s = s0 + l;
                int row = s / SPR, sub = s % SPR;
                int ksub = sub ^ (row & 7);
                async16(Ws + s0 * 16, (const char*)(wsrc + (size_t)row * K) + ksub * 16);
            }
        }
        asm volatile("s_waitcnt vmcnt(0)" ::: "memory");
        __syncthreads();

        half8 bfr[32];
        if constexpr (K == 128) {
#pragma unroll
            for (int ct = 0; ct < 8; ++ct)
#pragma unroll
                for (int ks = 0; ks < 4; ++ks) {
                    int row = ct * 16 + lr;
                    bfr[ct * 4 + ks] = *(const half8*)(Ws + row * ROWB +
                        ((ks * 64 + lk * 16) ^ ((row & 7) << 4)));
                }
        }

        for (int t = blockIdx.x; t < NNODES / 128; t += gridDim.x) {
            const int nbase = t * 128;
            __syncthreads();
            if constexpr (INF16) {
                const _Float16* xsrc = (const _Float16*)Xin;
                for (int s0 = wid * 64; s0 < 128 * SPR; s0 += 256) {
                    int s = s0 + l;
                    int row = s / SPR, sub = s % SPR;
                    int ksub = sub ^ (row & 7);
                    async16(Xs + s0 * 16,
                            (const char*)(xsrc + (size_t)(nbase + row) * xstride) + ksub * 16);
                }
                asm volatile("s_waitcnt vmcnt(0)" ::: "memory");
            } else {
                const float* xsrc = (const float*)Xin;
                for (int s = tid; s < 128 * SPR; s += 256) {
                    int row = s / SPR, sub = s % SPR;
                    int ksub = sub ^ (row & 7);
                    const float* p = xsrc + (size_t)(nbase + row) * xstride + ksub * 8;
                    float4 u = ((const float4*)p)[0];
                    float4 v = ((const float4*)p)[1];
                    half8 hv;
                    hv[0] = (_Float16)u.x; hv[1] = (_Float16)u.y;
                    hv[2] = (_Float16)u.z; hv[3] = (_Float16)u.w;
                    hv[4] = (_Float16)v.x; hv[5] = (_Float16)v.y;
                    hv[6] = (_Float16)v.z; hv[7] = (_Float16)v.w;
                    *(half8*)(Xs + s * 16) = hv;
                }
            }
            __syncthreads();

            float4v acc[2][8];
#pragma unroll
            for (int i = 0; i < 2; ++i)
#pragma unroll
                for (int j = 0; j < 8; ++j)
#pragma unroll
                    for (int q = 0; q < 4; ++q) acc[i][j][q] = 0.0f;

            if constexpr (K == 128) {
#pragma unroll
                for (int rt = 0; rt < 2; ++rt) {
                    half8 a[4];
                    int row = wrow + rt * 16 + lr;
#pragma unroll
                    for (int ks = 0; ks < 4; ++ks)
                        a[ks] = *(const half8*)(Xs + row * ROWB +
                            ((ks * 64 + lk * 16) ^ ((row & 7) << 4)));
#pragma unroll
                    for (int ct = 0; ct < 8; ++ct)
#pragma unroll
                        for (int ks = 0; ks < 4; ++ks)
                            acc[rt][ct] = __builtin_amdgcn_mfma_f32_16x16x32_f16(
                                a[ks], bfr[ct * 4 + ks], acc[rt][ct], 0, 0, 0);
                }
            } else {   // K == 256
#pragma unroll
                for (int kc = 0; kc < 2; ++kc) {
#pragma unroll
                    for (int ct = 0; ct < 8; ++ct)
#pragma unroll
                        for (int ks = 0; ks < 4; ++ks) {
                            int row = ct * 16 + lr;
                            bfr[ct * 4 + ks] = *(const half8*)(Ws + row * ROWB +
                                (((kc * 4 + ks) * 64 + lk * 16) ^ ((row & 7) << 4)));
                        }
#pragma unroll
                    for (int rt = 0; rt < 2; ++rt) {
                        half8 a[4];
                        int row = wrow + rt * 16 + lr;
#pragma unroll
                        for (int ks = 0; ks < 4; ++ks)
                            a[ks] = *(const half8*)(Xs + row * ROWB +
                                (((kc * 4 + ks) * 64 + lk * 16) ^ ((row & 7) << 4)));
#pragma unroll
                        for (int ct = 0; ct < 8; ++ct)
#pragma unroll
                            for (int ks = 0; ks < 4; ++ks)
                                acc[rt][ct] = __builtin_amdgcn_mfma_f32_16x16x32_f16(
                                    a[ks], bfr[ct * 4 + ks], acc[rt][ct], 0, 0, 0);
                    }
                }
            }

            if constexpr (FINAL) {
                const float bl3v = bl3p[0];
                float part[2][4];
#pragma unroll
                for (int rt = 0; rt < 2; ++rt)
#pragma unroll
                    for (int j = 0; j < 4; ++j) part[rt][j] = 0.0f;
#pragma unroll
                for (int rt = 0; rt < 2; ++rt)
#pragma unroll
                for (int ct = 0; ct < 8; ++ct) {
                    const int col = ct * 16 + lr;
                    const float wv = wl3[col];
                    const float bv = bias[col];
#pragma unroll
                    for (int j = 0; j < 4; ++j) {
                        float v = fmaxf(acc[rt][ct][j] + bv, 0.0f);
                        part[rt][j] = fmaf(v, wv, part[rt][j]);
                    }
                }
#pragma unroll
                for (int rt = 0; rt < 2; ++rt)
#pragma unroll
                for (int j = 0; j < 4; ++j) {
                    float s = part[rt][j];
                    s += __shfl_xor(s, 1);
                    s += __shfl_xor(s, 2);
                    s += __shfl_xor(s, 4);
                    s += __shfl_xor(s, 8);
                    if (lr == 0)
                        outf[nbase + wrow + rt * 16 + lk * 4 + j] = s + bl3v;
                }
            } else {
#pragma unroll
                for (int rt = 0; rt < 2; ++rt)
#pragma unroll
                for (int ct = 0; ct < 8; ++ct) {
                    const int col = ct * 16 + lr;
                    float bv = 0.0f;
                    if (bias) bv = bias[mc * 128 + col];
#pragma unroll
                    for (int j = 0; j < 4; ++j) {
                        const int n = nbase + wrow + rt * 16 + lk * 4 + j;
                        float v = acc[rt][ct][j] + bv;
                        if constexpr (SEGADD)
                            v += gproj[(size_t)seg[n] * 256 + mc * 128 + col];
                        if constexpr (RELU) v = fmaxf(v, 0.0f);
                        out1[(size_t)n * ostride + mc * 128 + col] = (_Float16)v;
                    }
                }
            }
        }
    }
}

// ---------------- fully-fused GRU (combined input weight Wc = Wih*W^T) ----------
// In-place h update; agg read from aggH (separate gather keeps occupancy high).
__global__ __launch_bounds__(512, 2) void gru_fused(
    const _Float16* __restrict__ agg,   // [N][128] = gathered h
    _Float16* h,                        // [N][128] in/out
    const _Float16* __restrict__ Wc,    // combined Wih*W^T fp16 [384][128]
    const _Float16* __restrict__ Whh,   // [384][128] fp16
    const float* __restrict__ bih, const float* __restrict__ bhh,
    int relu_out)
{
    __shared__ __align__(16) char As[128 * 256];
    __shared__ __align__(16) char Hs[128 * 256];
    __shared__ __align__(16) char Wb[2][128 * 256];
    const int tid = threadIdx.x, wid = tid >> 6, l = tid & 63;
    const int lr = l & 15, lk = l >> 4;
    const int wr = wid >> 1, wc = wid & 1;
    const int nbase = blockIdx.x * 128;

    auto stageT = [&](char* dst, const _Float16* src) {
        for (int s0 = wid * 64; s0 < 2048; s0 += 512) {
            int s = s0 + l;
            int row = s >> 4, sub = s & 15;
            int ksub = sub ^ (row & 7);
            async16(dst + s0 * 16, (const char*)(src + (size_t)row * 128) + ksub * 16);
        }
    };

    stageT(As, agg + (size_t)nbase * 128);
    stageT(Hs, h + (size_t)nbase * 128);
    stageT(Wb[0], Wc);

    float4v accA[2][4], accB[2][4], rg[2][4], zg[2][4];
    half8 aAg[2][4], aH[2][4];

#pragma unroll
    for (int c = 0; c < 6; ++c) {
        asm volatile("s_waitcnt vmcnt(0)" ::: "memory");
        __syncthreads();
        if (c < 5) {
            const int nc = c + 1;
            const _Float16* wsrc = ((nc & 1) ? Whh : Wc) + (size_t)(nc >> 1) * 16384;
            stageT(Wb[nc & 1], wsrc);
        }
        if (c == 0) {
#pragma unroll
            for (int rt = 0; rt < 2; ++rt) {
                const int row = wr * 32 + rt * 16 + lr;
#pragma unroll
                for (int ks = 0; ks < 4; ++ks) {
                    const int off = row * 256 + ((ks * 64 + lk * 16) ^ ((row & 7) << 4));
                    aAg[rt][ks] = *(const half8*)(As + off);
                    aH[rt][ks]  = *(const half8*)(Hs + off);
                }
            }
        }

        auto& af  = (c & 1) ? aH : aAg;
        auto& acc = (c & 1) ? accB : accA;
#pragma unroll
        for (int rt = 0; rt < 2; ++rt)
#pragma unroll
            for (int ct = 0; ct < 4; ++ct)
#pragma unroll
                for (int q = 0; q < 4; ++q) acc[rt][ct][q] = 0.0f;

        const char* wb = Wb[c & 1];
#pragma unroll
        for (int ct = 0; ct < 4; ++ct) {
            const int rowb = wc * 64 + ct * 16 + lr;
#pragma unroll
            for (int ks = 0; ks < 4; ++ks) {
                half8 b = *(const half8*)(wb + rowb * 256 +
                    ((ks * 64 + lk * 16) ^ ((rowb & 7) << 4)));
                acc[0][ct] = __builtin_amdgcn_mfma_f32_16x16x32_f16(af[0][ks], b, acc[0][ct], 0, 0, 0);
                acc[1][ct] = __builtin_amdgcn_mfma_f32_16x16x32_f16(af[1][ks], b, acc[1][ct], 0, 0, 0);
            }
        }

        if (c == 1) {
#pragma unroll
            for (int rt = 0; rt < 2; ++rt)
#pragma unroll
            for (int ct = 0; ct < 4; ++ct) {
                const int col = wc * 64 + ct * 16 + lr;
                const float bb = bih[col] + bhh[col];
#pragma unroll
                for (int j = 0; j < 4; ++j)
                    rg[rt][ct][j] = fsigm(accA[rt][ct][j] + accB[rt][ct][j] + bb);
            }
        } else if (c == 3) {
#pragma unroll
            for (int rt = 0; rt < 2; ++rt)
#pragma unroll
            for (int ct = 0; ct < 4; ++ct) {
                const int col = wc * 64 + ct * 16 + lr;
                const float bb = bih[128 + col] + bhh[128 + col];
#pragma unroll
                for (int j = 0; j < 4; ++j)
                    zg[rt][ct][j] = fsigm(accA[rt][ct][j] + accB[rt][ct][j] + bb);
            }
        } else if (c == 5) {
#pragma unroll
            for (int rt = 0; rt < 2; ++rt)
#pragma unroll
            for (int ct = 0; ct < 4; ++ct) {
                const int col = wc * 64 + ct * 16 + lr;
                const float bi = bih[256 + col], bh = bhh[256 + col];
                const int c2 = col * 2;
#pragma unroll
                for (int j = 0; j < 4; ++j) {
                    const int row = wr * 32 + rt * 16 + lk * 4 + j;
                    const int n = nbase + row;
                    float nv = ftanh(accA[rt][ct][j] + bi +
                                     rg[rt][ct][j] * (accB[rt][ct][j] + bh));
                    float hold = (float)*(const _Float16*)(Hs + row * 256 +
                        (((c2 >> 4) ^ (row & 7)) << 4) + (c2 & 15));
                    float z = zg[rt][ct][j];
                    float hn = (1.0f - z) * nv + z * hold;
                    if (relu_out) hn = fmaxf(hn, 0.0f);
                    h[(size_t)n * 128 + col] = (_Float16)hn;
                }
            }
        }
    }
}

// ---------------- segment sums (seg sorted) ----------------
__global__ __launch_bounds__(256) void seg_sum(const _Float16* __restrict__ x,
    const int* __restrict__ seg, float* __restrict__ sums, float* __restrict__ counts)
{
    int cg = threadIdx.x & 31, rs = threadIdx.x >> 5;
    int r0 = blockIdx.x * 256 + rs * 32;
    float a0 = 0, a1 = 0, a2 = 0, a3 = 0, cnt = 0;
    int cur = seg[r0];
    for (int i = 0; i < 32; ++i) {
        int n = r0 + i;
        int p = seg[n];
        if (p != cur) {
            atomicAdd(&sums[(size_t)cur * 128 + cg * 4 + 0], a0);
            atomicAdd(&sums[(size_t)cur * 128 + cg * 4 + 1], a1);
            atomicAdd(&sums[(size_t)cur * 128 + cg * 4 + 2], a2);
            atomicAdd(&sums[(size_t)cur * 128 + cg * 4 + 3], a3);
            if (cg == 0) atomicAdd(&counts[cur], cnt);
            a0 = a1 = a2 = a3 = 0; cnt = 0; cur = p;
        }
        half4v v = *(const half4v*)(x + (size_t)n * 128 + cg * 4);
        a0 += (float)v[0]; a1 += (float)v[1]; a2 += (float)v[2]; a3 += (float)v[3];
        cnt += 1.0f;
    }
    atomicAdd(&sums[(size_t)cur * 128 + cg * 4 + 0], a0);
    atomicAdd(&sums[(size_t)cur * 128 + cg * 4 + 1], a1);
    atomicAdd(&sums[(size_t)cur * 128 + cg * 4 + 2], a2);
    atomicAdd(&sums[(size_t)cur * 128 + cg * 4 + 3], a3);
    if (cg == 0) atomicAdd(&counts[cur], cnt);
}

// ---------------- gproj2[p][m] = cvec[m] + sum_t ymean[t]*Bf[t][m] ----------------
__global__ __launch_bounds__(256) void gproj2_kernel(const float* __restrict__ sums,
    const float* __restrict__ counts, const float* __restrict__ Bf,
    const float* __restrict__ cvec, float* __restrict__ gproj2)
{
    __shared__ float gm[128];
    int p = blockIdx.x, m = threadIdx.x;
    if (m < 128) gm[m] = sums[(size_t)p * 128 + m] / fmaxf(counts[p], 1.0f);
    __syncthreads();
    float acc = cvec[m];
#pragma unroll 8
    for (int k = 0; k < 128; ++k)
        acc = fmaf(gm[k], Bf[(size_t)k * 256 + m], acc);
    gproj2[(size_t)p * 256 + m] = acc;
}

extern "C" void kernel_launch(void* const* d_in, const int* in_sizes, int n_in,
                              void* d_out, int out_size, void* d_ws, size_t ws_size,
                              hipStream_t stream)
{
    (void)in_sizes; (void)n_in; (void)out_size; (void)ws_size;

    const float* G     = (const float*)d_in[0];
    const int*   ei    = (const int*)d_in[1];
    const float* ew    = (const float*)d_in[2];
    const int*   seg   = (const int*)d_in[4];
    const float* Wemb1 = (const float*)d_in[5];  const float* bemb1 = (const float*)d_in[6];
    const float* Wemb2 = (const float*)d_in[7];  const float* bemb2 = (const float*)d_in[8];
    const float* c1W   = (const float*)d_in[9];
    const float* c1Wih = (const float*)d_in[10]; const float* c1Whh = (const float*)d_in[11];
    const float* c1bih = (const float*)d_in[12]; const float* c1bhh = (const float*)d_in[13];
    const float* c2W   = (const float*)d_in[14];
    const float* c2Wih = (const float*)d_in[15]; const float* c2Whh = (const float*)d_in[16];
    const float* c2bih = (const float*)d_in[17]; const float* c2bhh = (const float*)d_in[18];
    const float* Wg1   = (const float*)d_in[19]; const float* bg1   = (const float*)d_in[20];
    const float* Wg2   = (const float*)d_in[21]; const float* bg2   = (const float*)d_in[22];
    const float* Wl    = (const float*)d_in[23]; const float* bl    = (const float*)d_in[24];
    const float* Wl2   = (const float*)d_in[25]; const float* bl2   = (const float*)d_in[26];
    const float* Wl3   = (const float*)d_in[27]; const float* bl3   = (const float*)d_in[28];

    const int* srcp = ei;
    const int* dstp = ei + NEDGES;

    char* ws = (char*)d_ws;
    const size_t NBH = (size_t)NNODES * 128 * 2;   // 32MB
    const size_t U1B = (size_t)NNODES * 256 * 2;   // 64MB

    _Float16* hA   = (_Float16*)ws;                 // h
    _Float16* hB   = (_Float16*)(ws + NBH);         // y
    _Float16* u1   = (_Float16*)(ws + 2 * NBH);     // [N][256]
    _Float16* aggH = (_Float16*)(ws + 2 * NBH + U1B); // [N][128]
    char*     aux  = ws + 3 * NBH + U1B;
    float* sums    = (float*)aux;                    // 32KB
    float* counts  = (float*)(aux + 32768);          // 1KB
    float* gproj2  = (float*)(aux + 33792);          // 64KB
    int*   deg     = (int*)(aux + 33792 + 65536);
    int*   offs    = deg + NNODES;
    int*   pos     = offs + NNODES + 64;
    int2*  csr     = (int2*)(pos + NNODES);
    char*  wtb     = (char*)csr + (size_t)NEDGES * 8;

    _Float16* wt_emb2 = (_Float16*)wtb;                    // [128][128]
    _Float16* wt_g1   = wt_emb2 + 16384;                   // [128][128]
    _Float16* wt_l2   = wt_g1 + 16384;                     // [128][256]
    _Float16* wt_hh1  = wt_l2 + 32768;                     // [384][128]
    _Float16* wt_hh2  = wt_hh1 + 49152;
    _Float16* wc0     = wt_hh2 + 49152;                    // [4][384][128]
    _Float16* At      = wc0 + 4 * 49152;                   // [256][128]
    float*    Bf      = (float*)(At + 32768);              // [128][256]
    float*    cvec    = Bf + 32768;                        // [256]

    // ---- weight prep (batched) ----
    tr_cvt2<<<128, 256, 0, stream>>>(Wemb2, Wg1, wt_emb2);
    tr_cvt<<<128, 256, 0, stream>>>(Wl2, wt_l2, 256, 128, 128);
    cvt16_2<<<384, 256, 0, stream>>>(c1Whh, c2Whh, wt_hh1);
    combine_gru4<<<768, 256, 0, stream>>>(c1Wih, c1W, c2Wih, c2W, wc0);
    combine_headA<<<128, 256, 0, stream>>>(Wg2, Wl, At);
    combine_headB<<<128, 256, 0, stream>>>(Wg2, Wl, Bf);
    combine_c<<<1, 256, 0, stream>>>(bg2, Wl, bl, cvec);

    // ---- CSR build ----
    hipMemsetAsync(deg, 0, NNODES * 4, stream);
    deg_hist<<<NEDGES / 256, 256, 0, stream>>>(dstp, deg);
    scan1<<<128, 256, 0, stream>>>(deg, offs, pos);
    scan2<<<1, 128, 0, stream>>>(pos);
    scan3<<<NNODES / 256, 256, 0, stream>>>(offs, pos, deg);
    csr_fill<<<NEDGES / 256, 256, 0, stream>>>(srcp, dstp, ew, deg, csr);

    // ---- embeddings ----
    emb1_kernel<<<NNODES * 128 / 256, 256, 0, stream>>>(G, Wemb1, bemb1, hB);
    gemm_mfma<128, 1, true, true, false, false><<<512, 256, 0, stream>>>(
        hB, 128, wt_emb2, bemb2, hA, 128, nullptr, nullptr, nullptr, nullptr, nullptr);

    // ---- 2 GatedGraphConv layers x 2 GRU iterations (separate gather, in-place h) --
    const _Float16* wcs[2][2] = { { wc0, wc0 + 49152 }, { wc0 + 2 * 49152, wc0 + 3 * 49152 } };
    const _Float16* whh[2] = { wt_hh1, wt_hh2 };
    const float* bihs[2] = { c1bih, c2bih };
    const float* bhhs[2] = { c1bhh, c2bhh };
    for (int cv = 0; cv < 2; ++cv) {
        for (int lyr = 0; lyr < 2; ++lyr) {
            gather_agg<<<NNODES / 4, 256, 0, stream>>>(hA, csr, offs, aggH);
            gru_fused<<<NNODES / 128, 512, 0, stream>>>(
                aggH, hA, wcs[cv][lyr], whh[cv], bihs[cv], bhhs[cv], (lyr == 1) ? 1 : 0);
        }
    }

    // ---- head: y = relu(x@Wg1+bg1); Wg2 folded into At/Bf/cvec ----
    gemm_mfma<128, 1, true, true, false, false><<<512, 256, 0, stream>>>(
        hA, 128, wt_g1, bg1, hB, 128, nullptr, nullptr, nullptr, nullptr, nullptr);

    hipMemsetAsync(sums, 0, 33792, stream);
    seg_sum<<<NNODES / 256, 256, 0, stream>>>(hB, seg, sums, counts);
    gproj2_kernel<<<NPROB, 256, 0, stream>>>(sums, counts, Bf, cvec, gproj2);

    // ---- u1 = relu(y @ At^T + gproj2[seg]) [N,256] ----
    gemm_mfma<128, 2, true, true, true, false><<<512, 256, 0, stream>>>(
        hB, 128, At, nullptr, u1, 256, gproj2, seg, nullptr, nullptr, nullptr);
    // ---- out[n] = relu(u1@Wl2+bl2) . Wl3 + bl3  (final dot fused) ----
    gemm_mfma<256, 1, true, true, false, true><<<256, 256, 0, stream>>>(
        u1, 256, wt_l2, bl2, nullptr, 0, nullptr, nullptr, Wl3, bl3, (float*)d_out);
}